// Round 12
// baseline (159.342 us; speedup 1.0000x reference)
//
#include <hip/hip_runtime.h>
#include <math.h>

#define FEAT 128
#define RSHIFT 6                 // 64 dsts per region
#define RDST 64
#define SRCMASK 0x3FFFFFFu       // src < 2^26
#define IMG_CAP 4096
#define MAXR 1024                // max regions for fast partition path
#define NB 256                   // partition blocks (== kB1 blockDim)

// ---------------- helpers ----------------

__device__ inline unsigned int pack_bf16(float a, float b) {
  unsigned int ua = __float_as_uint(a);
  unsigned int ub = __float_as_uint(b);
  ua = (ua + 0x7fffu + ((ua >> 16) & 1u)) >> 16;   // RNE
  ub = (ub + 0x7fffu + ((ub >> 16) & 1u)) >> 16;
  return ua | (ub << 16);
}

__device__ inline void acc8(float* acc, uint4 a) {
  acc[0] += __uint_as_float(a.x << 16);
  acc[1] += __uint_as_float(a.x & 0xffff0000u);
  acc[2] += __uint_as_float(a.y << 16);
  acc[3] += __uint_as_float(a.y & 0xffff0000u);
  acc[4] += __uint_as_float(a.z << 16);
  acc[5] += __uint_as_float(a.z & 0xffff0000u);
  acc[6] += __uint_as_float(a.w << 16);
  acc[7] += __uint_as_float(a.w & 0xffff0000u);
}

// ---------------- kA: softmax gather/exp | region histogram | bf16(h*exp) cast ----------------

__global__ void kA(const float* __restrict__ mask, const int* __restrict__ ids,
                   float* __restrict__ mv, float* __restrict__ pbuf, int ns,
                   const int* __restrict__ ed, int ne,
                   int gb, int hb, int* __restrict__ ghist, int chunk, int nr,
                   const float* __restrict__ h, uint2* __restrict__ hs2) {
  __shared__ int hist[MAXR];
  __shared__ float s[4];
  int bx = blockIdx.x;
  int t = threadIdx.x;
  if (bx < gb) {
    int i = bx * 256 + t;
    float v = 0.f;
    if (i < ns) { v = expf(mask[ids[i]]); mv[i] = v; }
#pragma unroll
    for (int o = 32; o >= 1; o >>= 1) v += __shfl_xor(v, o, 64);
    if ((t & 63) == 0) s[t >> 6] = v;
    __syncthreads();
    if (t == 0) pbuf[bx] = (s[0] + s[1]) + (s[2] + s[3]);
  } else if (bx < gb + hb) {
    int b = bx - gb;
    for (int i = t; i < nr; i += 256) hist[i] = 0;
    __syncthreads();
    int e0 = min(b * chunk, ne);
    int e1 = min(e0 + chunk, ne);
    for (int j = e0 + t * 4; j + 4 <= e1; j += 1024) {
      int4 d = *(const int4*)(ed + j);
      atomicAdd(&hist[d.x >> RSHIFT], 1);
      atomicAdd(&hist[d.y >> RSHIFT], 1);
      atomicAdd(&hist[d.z >> RSHIFT], 1);
      atomicAdd(&hist[d.w >> RSHIFT], 1);
    }
    int tb = e0 + ((e1 - e0) & ~3);
    for (int j = tb + t; j < e1; j += 256) atomicAdd(&hist[ed[j] >> RSHIFT], 1);
    __syncthreads();
    for (int i = t; i < nr; i += 256) ghist[(size_t)i * NB + b] = hist[i];
  } else {
    // cast h -> bf16 table pre-scaled by exp(mask[ids[row]]) (1/sum applied in agg epilogue)
    int i = (bx - gb - hb) * 256 + t;        // uint2 index; 32 per row
    int n2 = ns * (FEAT / 4);
    if (i < n2) {
      int row = i >> 5;
      float e = expf(mask[ids[row]]);        // broadcast load within 32-lane group
      float4 v = ((const float4*)h)[i];
      hs2[i] = make_uint2(pack_bf16(v.x * e, v.y * e), pack_bf16(v.z * e, v.w * e));
    }
  }
}

// fallback-only: per-dst degree count via global atomics
__global__ void k_deg(const int* __restrict__ ed, int* __restrict__ deg, int ne) {
  int i = (blockIdx.x * 256 + threadIdx.x) * 4;
  if (i + 4 <= ne) {
    int4 e4 = *(const int4*)(ed + i);
    atomicAdd(&deg[e4.x], 1); atomicAdd(&deg[e4.y], 1);
    atomicAdd(&deg[e4.z], 1); atomicAdd(&deg[e4.w], 1);
  } else {
    for (int j = i; j < ne; j++) atomicAdd(&deg[ed[j]], 1);
  }
}

// fallback-only standalone cast
__global__ void k_cast(const float* __restrict__ h, const float* __restrict__ mask,
                       const int* __restrict__ ids, uint2* __restrict__ hs2, int n2) {
  int i = blockIdx.x * 256 + threadIdx.x;
  if (i < n2) {
    int row = i >> 5;
    float e = expf(mask[ids[row]]);
    float4 v = ((const float4*)h)[i];
    hs2[i] = make_uint2(pack_bf16(v.x * e, v.y * e), pack_bf16(v.z * e, v.w * e));
  }
}

// ---------------- kB1: per-region ghist scan (block r) | ginv reduce (block nr) ----------------

__global__ __launch_bounds__(256) void kB1(int* __restrict__ ghist, int* __restrict__ rtot, int nr,
                                           const float* __restrict__ pbuf, float* __restrict__ ginv, int gb) {
  int r = blockIdx.x;
  int t = threadIdx.x;
  if (r == nr) {
    __shared__ float s[4];
    float v = 0.f;
    for (int i = t; i < gb; i += 256) v += pbuf[i];
#pragma unroll
    for (int o = 32; o >= 1; o >>= 1) v += __shfl_xor(v, o, 64);
    if ((t & 63) == 0) s[t >> 6] = v;
    __syncthreads();
    if (t == 0) ginv[0] = 1.0f / ((s[0] + s[1]) + (s[2] + s[3]));
    return;
  }
  __shared__ int ws[4];
  int lane = t & 63, wid = t >> 6;
  int v = ghist[(size_t)r * NB + t];
  int x = v;
#pragma unroll
  for (int o = 1; o < 64; o <<= 1) { int y = __shfl_up(x, o, 64); if (lane >= o) x += y; }
  if (lane == 63) ws[wid] = x;
  __syncthreads();
  int add = 0;
  if (wid > 0) add += ws[0];
  if (wid > 1) add += ws[1];
  if (wid > 2) add += ws[2];
  ghist[(size_t)r * NB + t] = x - v + add;    // exclusive prefix within region
  if (t == 255) rtot[r] = x + add;            // region total
}

// ---------------- generic single-block scan (fallback path) ----------------

__device__ inline void scan_body(const int* cnt, int* outp, int* cur, int n, int* total) {
  __shared__ int wsum[16];
  __shared__ int cbase;
  int t = threadIdx.x, lane = t & 63, wid = t >> 6;
  if (t == 0) cbase = 0;
  __syncthreads();
  for (int base = 0; base < n; base += 8192) {
    int v[8];
    int tot = 0;
    int idx0 = base + t * 8;
#pragma unroll
    for (int j = 0; j < 8; j++) { int ix = idx0 + j; v[j] = (ix < n) ? cnt[ix] : 0; tot += v[j]; }
    int x = tot;
#pragma unroll
    for (int o = 1; o < 64; o <<= 1) { int y = __shfl_up(x, o, 64); if (lane >= o) x += y; }
    if (lane == 63) wsum[wid] = x;
    __syncthreads();
    if (t < 16) {
      int w = wsum[t];
#pragma unroll
      for (int o = 1; o < 16; o <<= 1) { int y = __shfl_up(w, o, 64); if (t >= o) w += y; }
      wsum[t] = w;
    }
    __syncthreads();
    int wexcl = (wid == 0) ? 0 : wsum[wid - 1];
    int run = cbase + wexcl + (x - tot);
#pragma unroll
    for (int j = 0; j < 8; j++) {
      int ix = idx0 + j;
      if (ix < n) { outp[ix] = run; if (cur) cur[ix] = run; }
      run += v[j];
    }
    __syncthreads();
    if (t == 0) cbase += wsum[15];
    __syncthreads();
  }
  if (t == 0 && total) total[0] = cbase;
}

__global__ __launch_bounds__(1024) void k_scan(const int* __restrict__ cnt,
                                               int* __restrict__ outp, int* __restrict__ cur,
                                               int n, int* __restrict__ total) {
  scan_body(cnt, outp, cur, n, total);
}

__global__ void k_norm(float* __restrict__ mv, const float* __restrict__ ginv, int n) {
  int i = blockIdx.x * 256 + threadIdx.x;
  if (i < n) mv[i] *= ginv[0];
}

// ---------------- partition: local rbase scan + mv normalize + packed-edge scatter ----------------

__global__ __launch_bounds__(256) void k_part(const int* __restrict__ es, const int* __restrict__ ed,
                                              const int* __restrict__ ghist, const int* __restrict__ rtot,
                                              int* __restrict__ rbase,
                                              unsigned int* __restrict__ csr, int ne, int chunk, int nr,
                                              float* __restrict__ mv, int ns, const float* __restrict__ ginv) {
  __shared__ int cur[MAXR];
  __shared__ int rb[MAXR + 1];
  __shared__ int ws[4];
  int b = blockIdx.x, t = threadIdx.x;
  int lane = t & 63, wid = t >> 6;

  // local exclusive scan of rtot[0..nr) -> rb[0..nr]  (nr <= MAXR = 256*4)
  int i0 = t * 4;
  int v0 = 0, v1 = 0, v2 = 0, v3 = 0;
  if (i0 + 0 < nr) v0 = rtot[i0 + 0];
  if (i0 + 1 < nr) v1 = rtot[i0 + 1];
  if (i0 + 2 < nr) v2 = rtot[i0 + 2];
  if (i0 + 3 < nr) v3 = rtot[i0 + 3];
  int tot = v0 + v1 + v2 + v3;
  int x = tot;
#pragma unroll
  for (int o = 1; o < 64; o <<= 1) { int y = __shfl_up(x, o, 64); if (lane >= o) x += y; }
  if (lane == 63) ws[wid] = x;
  __syncthreads();
  int add = 0;
  if (wid > 0) add += ws[0];
  if (wid > 1) add += ws[1];
  if (wid > 2) add += ws[2];
  int run = add + x - tot;
  if (i0 + 0 <= nr) rb[i0 + 0] = run; run += v0;
  if (i0 + 1 <= nr) rb[i0 + 1] = run; run += v1;
  if (i0 + 2 <= nr) rb[i0 + 2] = run; run += v2;
  if (i0 + 3 <= nr) rb[i0 + 3] = run;
  if (t == 0) rb[nr] = ws[0] + ws[1] + ws[2] + ws[3];
  __syncthreads();

  // block 0 publishes rbase for k_aggr
  if (b == 0) {
    for (int i = t; i <= nr; i += 256) rbase[i] = rb[i];
  }

  float gi = ginv[0];
  for (int i = b * 256 + t; i < ns; i += NB * 256) mv[i] *= gi;
  for (int i = t; i < nr; i += 256) cur[i] = rb[i] + ghist[(size_t)i * NB + b];
  __syncthreads();

  int e0 = min(b * chunk, ne);
  int e1 = min(e0 + chunk, ne);
  for (int j = e0 + t * 4; j + 4 <= e1; j += 1024) {
    int4 s = *(const int4*)(es + j);
    int4 d = *(const int4*)(ed + j);
    int p0 = atomicAdd(&cur[d.x >> RSHIFT], 1);
    int p1 = atomicAdd(&cur[d.y >> RSHIFT], 1);
    int p2 = atomicAdd(&cur[d.z >> RSHIFT], 1);
    int p3 = atomicAdd(&cur[d.w >> RSHIFT], 1);
    csr[p0] = (unsigned int)s.x | ((unsigned int)(d.x & (RDST - 1)) << 26);
    csr[p1] = (unsigned int)s.y | ((unsigned int)(d.y & (RDST - 1)) << 26);
    csr[p2] = (unsigned int)s.z | ((unsigned int)(d.z & (RDST - 1)) << 26);
    csr[p3] = (unsigned int)s.w | ((unsigned int)(d.w & (RDST - 1)) << 26);
  }
  int tb = e0 + ((e1 - e0) & ~3);
  for (int j = tb + t; j < e1; j += 256) {
    int d = ed[j];
    int p = atomicAdd(&cur[d >> RSHIFT], 1);
    csr[p] = (unsigned int)es[j] | ((unsigned int)(d & (RDST - 1)) << 26);
  }
}

// fallback: per-dst global-atomic scatter (only if nr > MAXR)
__global__ void k_scatter(const int* __restrict__ es, const int* __restrict__ ed,
                          int* __restrict__ cur, unsigned int* __restrict__ csr, int ne) {
  int i = (blockIdx.x * 256 + threadIdx.x) * 4;
  if (i + 4 <= ne) {
    int4 s4 = *(const int4*)(es + i);
    int4 d4 = *(const int4*)(ed + i);
    csr[atomicAdd(&cur[d4.x], 1)] = (unsigned int)s4.x;
    csr[atomicAdd(&cur[d4.y], 1)] = (unsigned int)s4.y;
    csr[atomicAdd(&cur[d4.z], 1)] = (unsigned int)s4.z;
    csr[atomicAdd(&cur[d4.w], 1)] = (unsigned int)s4.w;
  } else {
    for (int j = i; j < ne; j++) csr[atomicAdd(&cur[ed[j]], 1)] = (unsigned int)es[j];
  }
}

// ---------------- fused regroup + aggregation: one region per block ----------------

__global__ __launch_bounds__(512) void k_aggr(const unsigned int* __restrict__ csr,
                                              const int* __restrict__ rbase,
                                              const unsigned int* __restrict__ hs,
                                              const float* __restrict__ ginv,
                                              float* __restrict__ out, int nd) {
  __shared__ unsigned int img[IMG_CAP];
  __shared__ int cnt[RDST];
  __shared__ int off[RDST];
  __shared__ int rpl[RDST + 1];
  int r = blockIdx.x;
  int t = threadIdx.x;
  int wave = t >> 6, lane = t & 63;
  int start = rbase[r], end = rbase[r + 1];
  int n = end - start;
  int d0 = r << RSHIFT;
  int ndst = min(RDST, nd - d0);
  float gi = ginv[0];
  int q = lane >> 4;
  int fw = (lane & 15) * 4;

  if (n <= IMG_CAP) {
    // ---- LDS counting-sort of region segment by dlow ----
    if (t < RDST) cnt[t] = 0;
    __syncthreads();
    for (int i = t; i < n; i += 512) atomicAdd(&cnt[(csr[start + i] >> 26) & (RDST - 1)], 1);
    __syncthreads();
    if (t < RDST) {
      int x = cnt[t];
      int inc = x;
#pragma unroll
      for (int o = 1; o < RDST; o <<= 1) { int y = __shfl_up(inc, o, 64); if (t >= o) inc += y; }
      rpl[t] = inc - x;
      off[t] = inc - x;
      if (t == RDST - 1) rpl[RDST] = inc;
    }
    __syncthreads();
    for (int i = t; i < n; i += 512) {
      unsigned int v = csr[start + i];
      int p = atomicAdd(&off[(v >> 26) & (RDST - 1)], 1);
      img[p] = v;
    }
    __syncthreads();

    // ---- aggregate: 8 waves, each handles dsts wave, wave+8, ... ----
    for (int dd = wave; dd < ndst; dd += 8) {
      int beg = rpl[dd], endl = rpl[dd + 1];
      float sc = gi / fmaxf((float)(endl - beg), 1.0f);
      float acc[8] = {0, 0, 0, 0, 0, 0, 0, 0};
      int e = beg;
      for (; e + 16 <= endl; e += 16) {
        int s0 = img[e + q] & SRCMASK;
        int s1 = img[e + 4 + q] & SRCMASK;
        int s2 = img[e + 8 + q] & SRCMASK;
        int s3 = img[e + 12 + q] & SRCMASK;
        uint4 a = *(const uint4*)(hs + (size_t)s0 * 64 + fw);
        uint4 b = *(const uint4*)(hs + (size_t)s1 * 64 + fw);
        uint4 c = *(const uint4*)(hs + (size_t)s2 * 64 + fw);
        uint4 dv = *(const uint4*)(hs + (size_t)s3 * 64 + fw);
        acc8(acc, a); acc8(acc, b); acc8(acc, c); acc8(acc, dv);
      }
      for (; e + 4 <= endl; e += 4) {
        int s0 = img[e + q] & SRCMASK;
        uint4 a = *(const uint4*)(hs + (size_t)s0 * 64 + fw);
        acc8(acc, a);
      }
      int rem = endl - e;
      if (q < rem) {
        int s0 = img[e + q] & SRCMASK;
        uint4 a = *(const uint4*)(hs + (size_t)s0 * 64 + fw);
        acc8(acc, a);
      }
#pragma unroll
      for (int j = 0; j < 8; j++) {
        acc[j] += __shfl_xor(acc[j], 16, 64);
        acc[j] += __shfl_xor(acc[j], 32, 64);
      }
      if (lane < 16) {
        float4 o0 = make_float4(acc[0] * sc, acc[1] * sc, acc[2] * sc, acc[3] * sc);
        float4 o1 = make_float4(acc[4] * sc, acc[5] * sc, acc[6] * sc, acc[7] * sc);
        float* p = out + (size_t)(d0 + dd) * FEAT + fw * 2;
        *(float4*)p = o0;
        *(float4*)(p + 4) = o1;
      }
    }
  } else {
    // rare: region too big for LDS — filter-scan global segment per dst
    for (int dd = wave; dd < ndst; dd += 8) {
      unsigned int dl = (unsigned int)dd;
      float a0 = 0.f, a1 = 0.f;
      int c = 0;
      for (int e = start; e < end; ++e) {
        unsigned int v = csr[e];
        if (((v >> 26) & (RDST - 1)) == dl) {
          c++;
          unsigned int u = hs[(size_t)(v & SRCMASK) * 64 + lane];
          a0 += __uint_as_float(u << 16);
          a1 += __uint_as_float(u & 0xffff0000u);
        }
      }
      float sc = gi / fmaxf((float)c, 1.0f);
      *(float2*)(out + (size_t)(d0 + dd) * FEAT + lane * 2) = make_float2(a0 * sc, a1 * sc);
    }
  }
}

// fallback rp-based aggregation (only if nr > MAXR; csr holds plain src)
__global__ __launch_bounds__(256) void k_agg_bf(const int* __restrict__ rp, const unsigned int* __restrict__ csr,
                                                const unsigned int* __restrict__ hs,
                                                const float* __restrict__ ginv,
                                                float* __restrict__ out, int nd) {
  int d = blockIdx.x * 4 + (threadIdx.x >> 6);
  if (d >= nd) return;
  int lane = threadIdx.x & 63;
  float gi = ginv[0];
  int beg = rp[d], end = rp[d + 1];
  float sc = gi / fmaxf((float)(end - beg), 1.0f);
  int q = lane >> 4;
  int fw = (lane & 15) * 4;
  float acc[8] = {0, 0, 0, 0, 0, 0, 0, 0};
  int e = beg;
  for (; e + 16 <= end; e += 16) {
    int s0 = csr[e + q] & SRCMASK;
    int s1 = csr[e + 4 + q] & SRCMASK;
    int s2 = csr[e + 8 + q] & SRCMASK;
    int s3 = csr[e + 12 + q] & SRCMASK;
    uint4 a = *(const uint4*)(hs + (size_t)s0 * 64 + fw);
    uint4 b = *(const uint4*)(hs + (size_t)s1 * 64 + fw);
    uint4 c = *(const uint4*)(hs + (size_t)s2 * 64 + fw);
    uint4 dd = *(const uint4*)(hs + (size_t)s3 * 64 + fw);
    acc8(acc, a); acc8(acc, b); acc8(acc, c); acc8(acc, dd);
  }
  for (; e + 4 <= end; e += 4) {
    int s0 = csr[e + q] & SRCMASK;
    uint4 a = *(const uint4*)(hs + (size_t)s0 * 64 + fw);
    acc8(acc, a);
  }
  int rem = end - e;
  if (q < rem) {
    int s0 = csr[e + q] & SRCMASK;
    uint4 a = *(const uint4*)(hs + (size_t)s0 * 64 + fw);
    acc8(acc, a);
  }
#pragma unroll
  for (int j = 0; j < 8; j++) {
    acc[j] += __shfl_xor(acc[j], 16, 64);
    acc[j] += __shfl_xor(acc[j], 32, 64);
  }
  if (lane < 16) {
    float4 o0 = make_float4(acc[0] * sc, acc[1] * sc, acc[2] * sc, acc[3] * sc);
    float4 o1 = make_float4(acc[4] * sc, acc[5] * sc, acc[6] * sc, acc[7] * sc);
    float* p = out + (size_t)d * FEAT + fw * 2;
    *(float4*)p = o0;
    *(float4*)(p + 4) = o1;
  }
}

// fallback f32 aggregation (if workspace too small for hs; mv already normalized)
__global__ __launch_bounds__(256) void k_agg_f32(const int* __restrict__ rp, const unsigned int* __restrict__ csr,
                                                 const float* __restrict__ h, const float* __restrict__ mv,
                                                 float* __restrict__ rst, int nd) {
  int d = blockIdx.x * 4 + (threadIdx.x >> 6);
  if (d >= nd) return;
  int lane = threadIdx.x & 63;
  float ax = 0.f, ay = 0.f;
  int beg = rp[d], end = rp[d + 1];
  float inv = 1.0f / fmaxf((float)(end - beg), 1.0f);
  for (int e = beg; e < end; ++e) {
    int s = csr[e] & SRCMASK;
    float m = mv[s];
    float2 vv = *(const float2*)(h + (size_t)s * FEAT + lane * 2);
    ax += vv.x * m; ay += vv.y * m;
  }
  *(float2*)(rst + (size_t)d * FEAT + lane * 2) = make_float2(ax * inv, ay * inv);
}

// ---------------- in-place dense transform: out = rst @ W + b ----------------

__global__ __launch_bounds__(256) void k_gemm(float* __restrict__ out, const float* __restrict__ W,
                                              const float* __restrict__ b, int nd) {
  __shared__ float Ws[FEAT * FEAT];
  __shared__ float Rs[32][FEAT];
  int t = threadIdx.x;
  for (int i = t * 4; i < FEAT * FEAT; i += 1024) *(float4*)(Ws + i) = *(const float4*)(W + i);
  int c0 = (t & 31) * 4;
  int rg = (t >> 5) * 4;
  float4 bb = *(const float4*)(b + c0);
  for (int ch = 0; ch < 4; ch++) {
    int r0 = blockIdx.x * 128 + ch * 32;
    if (r0 >= nd) break;
    int rows = min(32, nd - r0);
    __syncthreads();
    for (int i = t; i < rows * FEAT; i += 256) Rs[i >> 7][i & 127] = out[(size_t)r0 * FEAT + i];
    __syncthreads();
    float acc[4][4];
#pragma unroll
    for (int i = 0; i < 4; i++) { acc[i][0] = bb.x; acc[i][1] = bb.y; acc[i][2] = bb.z; acc[i][3] = bb.w; }
    for (int k = 0; k < FEAT; k += 4) {
#pragma unroll
      for (int kk = 0; kk < 4; kk++) {
        float4 wv = *(const float4*)(&Ws[(k + kk) * FEAT + c0]);
#pragma unroll
        for (int i = 0; i < 4; i++) {
          float rv = Rs[rg + i][k + kk];
          acc[i][0] += rv * wv.x;
          acc[i][1] += rv * wv.y;
          acc[i][2] += rv * wv.z;
          acc[i][3] += rv * wv.w;
        }
      }
    }
#pragma unroll
    for (int i = 0; i < 4; i++) {
      int r = rg + i;
      if (r < rows) *(float4*)(out + (size_t)(r0 + r) * FEAT + c0) = *(float4*)acc[i];
    }
  }
}

// ---------------- launcher ----------------

extern "C" void kernel_launch(void* const* d_in, const int* in_sizes, int n_in,
                              void* d_out, int out_size, void* d_ws, size_t ws_size,
                              hipStream_t stream) {
  const float* h    = (const float*)d_in[0];
  const int*   ids  = (const int*)d_in[1];
  const int*   es   = (const int*)d_in[2];
  const int*   ed   = (const int*)d_in[3];
  const float* mask = (const float*)d_in[4];
  const float* W    = (const float*)d_in[5];
  const float* b    = (const float*)d_in[6];
  float* out = (float*)d_out;

  const int NS = in_sizes[1];
  const int E  = in_sizes[2];
  const int H  = in_sizes[6];
  const int ND = (out_size - NS) / H;
  const int NR = (ND + RDST - 1) >> RSHIFT;
  const bool use_part = (NR <= MAXR);

  float* mv = out + (size_t)ND * H;

  char* w = (char*)d_ws;
  size_t used = 0;
  auto carve = [&](size_t bytes) -> char* {
    char* p = w + used;
    used += (bytes + 255) & ~(size_t)255;
    return p;
  };
  float* pbuf = (float*)carve(4096 * sizeof(float));
  float* ginv = (float*)carve(256);
  int* rp    = (int*)carve((size_t)(ND + 1) * sizeof(int));
  int* rtot  = (int*)carve((size_t)NR * sizeof(int));
  int* rbase = (int*)carve((size_t)(NR + 1) * sizeof(int));
  int* deg   = (int*)carve((size_t)ND * sizeof(int));   // fallback only
  int* cur   = (int*)carve((size_t)ND * sizeof(int));   // fallback only
  int* ghist = (int*)carve((size_t)NR * NB * sizeof(int));
  unsigned int* csr = (unsigned int*)carve((size_t)E * sizeof(int));
  size_t hs_bytes = (size_t)NS * FEAT * 2;
  unsigned int* hs = nullptr;
  if (used + hs_bytes + 256 <= ws_size) hs = (unsigned int*)carve(hs_bytes);

  const int gb = (NS + 255) / 256;
  const int db = ((E + 3) / 4 + 255) / 256;
  const int chunk = ((E + NB - 1) / NB + 3) & ~3;
  const int hb = use_part ? NB : 0;
  const int n2 = hs ? NS * (FEAT / 4) : 0;
  const int cb = hs ? (n2 + 255) / 256 : 0;

  kA<<<gb + hb + cb, 256, 0, stream>>>(mask, ids, mv, pbuf, NS, ed, E, gb, hb,
                                       ghist, chunk, NR, h, (uint2*)hs);

  if (use_part && hs) {
    kB1<<<NR + 1, 256, 0, stream>>>(ghist, rtot, NR, pbuf, ginv, gb);
    k_part<<<NB, 256, 0, stream>>>(es, ed, ghist, rtot, rbase, csr, E, chunk, NR, mv, NS, ginv);
    k_aggr<<<NR, 512, 0, stream>>>(csr, rbase, hs, ginv, out, ND);
  } else {
    kB1<<<1, 256, 0, stream>>>(ghist, rtot, 0, pbuf, ginv, gb);
    hipMemsetAsync(deg, 0, (size_t)ND * sizeof(int), stream);
    k_deg<<<db, 256, 0, stream>>>(ed, deg, E);
    k_scan<<<1, 1024, 0, stream>>>(deg, rp, cur, ND, rp + ND);
    k_norm<<<(NS + 255) / 256, 256, 0, stream>>>(mv, ginv, NS);
    if (hs) k_cast<<<(n2 + 255) / 256, 256, 0, stream>>>(h, mask, ids, (uint2*)hs, n2);
    k_scatter<<<db, 256, 0, stream>>>(es, ed, cur, csr, E);
    if (hs) k_agg_bf<<<(ND + 3) / 4, 256, 0, stream>>>(rp, csr, hs, ginv, out, ND);
    else    k_agg_f32<<<(ND + 3) / 4, 256, 0, stream>>>(rp, csr, h, mv, out, ND);
  }
  k_gemm<<<(ND + 127) / 128, 256, 0, stream>>>(out, W, b, ND);
}

// Round 13
// 156.534 us; speedup vs baseline: 1.0179x; 1.0179x over previous
//
#include <hip/hip_runtime.h>
#include <math.h>

#define FEAT 128
#define RSHIFT 6                 // 64 dsts per region
#define RDST 64
#define SRCMASK 0x3FFFFFFu       // src < 2^26
#define IMG_CAP 4096
#define MAXR 1024                // max regions for fast partition path
#define NB 256                   // partition blocks (== kB1 blockDim)

// ---------------- helpers ----------------

__device__ inline unsigned int pack_bf16(float a, float b) {
  unsigned int ua = __float_as_uint(a);
  unsigned int ub = __float_as_uint(b);
  ua = (ua + 0x7fffu + ((ua >> 16) & 1u)) >> 16;   // RNE
  ub = (ub + 0x7fffu + ((ub >> 16) & 1u)) >> 16;
  return ua | (ub << 16);
}

__device__ inline void acc8(float* acc, uint4 a) {
  acc[0] += __uint_as_float(a.x << 16);
  acc[1] += __uint_as_float(a.x & 0xffff0000u);
  acc[2] += __uint_as_float(a.y << 16);
  acc[3] += __uint_as_float(a.y & 0xffff0000u);
  acc[4] += __uint_as_float(a.z << 16);
  acc[5] += __uint_as_float(a.z & 0xffff0000u);
  acc[6] += __uint_as_float(a.w << 16);
  acc[7] += __uint_as_float(a.w & 0xffff0000u);
}

// ---------------- kA: softmax gather/exp | region histogram | bf16(h*exp) cast ----------------

__global__ void kA(const float* __restrict__ mask, const int* __restrict__ ids,
                   float* __restrict__ mv, float* __restrict__ pbuf, int ns,
                   const int* __restrict__ ed, int ne,
                   int gb, int hb, int* __restrict__ ghist, int chunk, int nr,
                   const float* __restrict__ h, uint2* __restrict__ hs2) {
  __shared__ int hist[MAXR];
  __shared__ float s[4];
  int bx = blockIdx.x;
  int t = threadIdx.x;
  if (bx < gb) {
    int i = bx * 256 + t;
    float v = 0.f;
    if (i < ns) { v = expf(mask[ids[i]]); mv[i] = v; }
#pragma unroll
    for (int o = 32; o >= 1; o >>= 1) v += __shfl_xor(v, o, 64);
    if ((t & 63) == 0) s[t >> 6] = v;
    __syncthreads();
    if (t == 0) pbuf[bx] = (s[0] + s[1]) + (s[2] + s[3]);
  } else if (bx < gb + hb) {
    int b = bx - gb;
    for (int i = t; i < nr; i += 256) hist[i] = 0;
    __syncthreads();
    int e0 = min(b * chunk, ne);
    int e1 = min(e0 + chunk, ne);
    for (int j = e0 + t * 4; j + 4 <= e1; j += 1024) {
      int4 d = *(const int4*)(ed + j);
      atomicAdd(&hist[d.x >> RSHIFT], 1);
      atomicAdd(&hist[d.y >> RSHIFT], 1);
      atomicAdd(&hist[d.z >> RSHIFT], 1);
      atomicAdd(&hist[d.w >> RSHIFT], 1);
    }
    int tb = e0 + ((e1 - e0) & ~3);
    for (int j = tb + t; j < e1; j += 256) atomicAdd(&hist[ed[j] >> RSHIFT], 1);
    __syncthreads();
    for (int i = t; i < nr; i += 256) ghist[(size_t)i * NB + b] = hist[i];
  } else {
    // cast h -> bf16 table pre-scaled by exp(mask[ids[row]]) (1/sum applied in agg epilogue)
    int i = (bx - gb - hb) * 256 + t;        // uint2 index; 32 per row
    int n2 = ns * (FEAT / 4);
    if (i < n2) {
      int row = i >> 5;
      float e = expf(mask[ids[row]]);        // broadcast load within 32-lane group
      float4 v = ((const float4*)h)[i];
      hs2[i] = make_uint2(pack_bf16(v.x * e, v.y * e), pack_bf16(v.z * e, v.w * e));
    }
  }
}

// fallback-only: per-dst degree count via global atomics
__global__ void k_deg(const int* __restrict__ ed, int* __restrict__ deg, int ne) {
  int i = (blockIdx.x * 256 + threadIdx.x) * 4;
  if (i + 4 <= ne) {
    int4 e4 = *(const int4*)(ed + i);
    atomicAdd(&deg[e4.x], 1); atomicAdd(&deg[e4.y], 1);
    atomicAdd(&deg[e4.z], 1); atomicAdd(&deg[e4.w], 1);
  } else {
    for (int j = i; j < ne; j++) atomicAdd(&deg[ed[j]], 1);
  }
}

// fallback-only standalone cast
__global__ void k_cast(const float* __restrict__ h, const float* __restrict__ mask,
                       const int* __restrict__ ids, uint2* __restrict__ hs2, int n2) {
  int i = blockIdx.x * 256 + threadIdx.x;
  if (i < n2) {
    int row = i >> 5;
    float e = expf(mask[ids[row]]);
    float4 v = ((const float4*)h)[i];
    hs2[i] = make_uint2(pack_bf16(v.x * e, v.y * e), pack_bf16(v.z * e, v.w * e));
  }
}

// ---------------- kB1: per-region ghist scan (block r) | ginv reduce (block nr) ----------------

__global__ __launch_bounds__(256) void kB1(int* __restrict__ ghist, int* __restrict__ rtot, int nr,
                                           const float* __restrict__ pbuf, float* __restrict__ ginv, int gb) {
  int r = blockIdx.x;
  int t = threadIdx.x;
  if (r == nr) {
    __shared__ float s[4];
    float v = 0.f;
    for (int i = t; i < gb; i += 256) v += pbuf[i];
#pragma unroll
    for (int o = 32; o >= 1; o >>= 1) v += __shfl_xor(v, o, 64);
    if ((t & 63) == 0) s[t >> 6] = v;
    __syncthreads();
    if (t == 0) ginv[0] = 1.0f / ((s[0] + s[1]) + (s[2] + s[3]));
    return;
  }
  __shared__ int ws[4];
  int lane = t & 63, wid = t >> 6;
  int v = ghist[(size_t)r * NB + t];
  int x = v;
#pragma unroll
  for (int o = 1; o < 64; o <<= 1) { int y = __shfl_up(x, o, 64); if (lane >= o) x += y; }
  if (lane == 63) ws[wid] = x;
  __syncthreads();
  int add = 0;
  if (wid > 0) add += ws[0];
  if (wid > 1) add += ws[1];
  if (wid > 2) add += ws[2];
  ghist[(size_t)r * NB + t] = x - v + add;    // exclusive prefix within region
  if (t == 255) rtot[r] = x + add;            // region total
}

// ---------------- generic single-block scan (fallback path) ----------------

__device__ inline void scan_body(const int* cnt, int* outp, int* cur, int n, int* total) {
  __shared__ int wsum[16];
  __shared__ int cbase;
  int t = threadIdx.x, lane = t & 63, wid = t >> 6;
  if (t == 0) cbase = 0;
  __syncthreads();
  for (int base = 0; base < n; base += 8192) {
    int v[8];
    int tot = 0;
    int idx0 = base + t * 8;
#pragma unroll
    for (int j = 0; j < 8; j++) { int ix = idx0 + j; v[j] = (ix < n) ? cnt[ix] : 0; tot += v[j]; }
    int x = tot;
#pragma unroll
    for (int o = 1; o < 64; o <<= 1) { int y = __shfl_up(x, o, 64); if (lane >= o) x += y; }
    if (lane == 63) wsum[wid] = x;
    __syncthreads();
    if (t < 16) {
      int w = wsum[t];
#pragma unroll
      for (int o = 1; o < 16; o <<= 1) { int y = __shfl_up(w, o, 64); if (t >= o) w += y; }
      wsum[t] = w;
    }
    __syncthreads();
    int wexcl = (wid == 0) ? 0 : wsum[wid - 1];
    int run = cbase + wexcl + (x - tot);
#pragma unroll
    for (int j = 0; j < 8; j++) {
      int ix = idx0 + j;
      if (ix < n) { outp[ix] = run; if (cur) cur[ix] = run; }
      run += v[j];
    }
    __syncthreads();
    if (t == 0) cbase += wsum[15];
    __syncthreads();
  }
  if (t == 0 && total) total[0] = cbase;
}

__global__ __launch_bounds__(1024) void k_scan(const int* __restrict__ cnt,
                                               int* __restrict__ outp, int* __restrict__ cur,
                                               int n, int* __restrict__ total) {
  scan_body(cnt, outp, cur, n, total);
}

__global__ void k_norm(float* __restrict__ mv, const float* __restrict__ ginv, int n) {
  int i = blockIdx.x * 256 + threadIdx.x;
  if (i < n) mv[i] *= ginv[0];
}

// ---------------- partition: local rbase scan + mv normalize + packed-edge scatter ----------------

__global__ __launch_bounds__(256) void k_part(const int* __restrict__ es, const int* __restrict__ ed,
                                              const int* __restrict__ ghist, const int* __restrict__ rtot,
                                              int* __restrict__ rbase,
                                              unsigned int* __restrict__ csr, int ne, int chunk, int nr,
                                              float* __restrict__ mv, int ns, const float* __restrict__ ginv) {
  __shared__ int cur[MAXR];
  __shared__ int rb[MAXR + 1];
  __shared__ int ws[4];
  int b = blockIdx.x, t = threadIdx.x;
  int lane = t & 63, wid = t >> 6;

  // local exclusive scan of rtot[0..nr) -> rb[0..nr]  (nr <= MAXR = 256*4)
  int i0 = t * 4;
  int v0 = 0, v1 = 0, v2 = 0, v3 = 0;
  if (i0 + 0 < nr) v0 = rtot[i0 + 0];
  if (i0 + 1 < nr) v1 = rtot[i0 + 1];
  if (i0 + 2 < nr) v2 = rtot[i0 + 2];
  if (i0 + 3 < nr) v3 = rtot[i0 + 3];
  int tot = v0 + v1 + v2 + v3;
  int x = tot;
#pragma unroll
  for (int o = 1; o < 64; o <<= 1) { int y = __shfl_up(x, o, 64); if (lane >= o) x += y; }
  if (lane == 63) ws[wid] = x;
  __syncthreads();
  int add = 0;
  if (wid > 0) add += ws[0];
  if (wid > 1) add += ws[1];
  if (wid > 2) add += ws[2];
  int run = add + x - tot;
  if (i0 + 0 <= nr) rb[i0 + 0] = run; run += v0;
  if (i0 + 1 <= nr) rb[i0 + 1] = run; run += v1;
  if (i0 + 2 <= nr) rb[i0 + 2] = run; run += v2;
  if (i0 + 3 <= nr) rb[i0 + 3] = run;
  if (t == 0) rb[nr] = ws[0] + ws[1] + ws[2] + ws[3];
  __syncthreads();

  // block 0 publishes rbase for k_group
  if (b == 0) {
    for (int i = t; i <= nr; i += 256) rbase[i] = rb[i];
  }

  float gi = ginv[0];
  for (int i = b * 256 + t; i < ns; i += NB * 256) mv[i] *= gi;
  for (int i = t; i < nr; i += 256) cur[i] = rb[i] + ghist[(size_t)i * NB + b];
  __syncthreads();

  int e0 = min(b * chunk, ne);
  int e1 = min(e0 + chunk, ne);
  for (int j = e0 + t * 4; j + 4 <= e1; j += 1024) {
    int4 s = *(const int4*)(es + j);
    int4 d = *(const int4*)(ed + j);
    int p0 = atomicAdd(&cur[d.x >> RSHIFT], 1);
    int p1 = atomicAdd(&cur[d.y >> RSHIFT], 1);
    int p2 = atomicAdd(&cur[d.z >> RSHIFT], 1);
    int p3 = atomicAdd(&cur[d.w >> RSHIFT], 1);
    csr[p0] = (unsigned int)s.x | ((unsigned int)(d.x & (RDST - 1)) << 26);
    csr[p1] = (unsigned int)s.y | ((unsigned int)(d.y & (RDST - 1)) << 26);
    csr[p2] = (unsigned int)s.z | ((unsigned int)(d.z & (RDST - 1)) << 26);
    csr[p3] = (unsigned int)s.w | ((unsigned int)(d.w & (RDST - 1)) << 26);
  }
  int tb = e0 + ((e1 - e0) & ~3);
  for (int j = tb + t; j < e1; j += 256) {
    int d = ed[j];
    int p = atomicAdd(&cur[d >> RSHIFT], 1);
    csr[p] = (unsigned int)es[j] | ((unsigned int)(d & (RDST - 1)) << 26);
  }
}

// fallback: per-dst global-atomic scatter (only if nr > MAXR)
__global__ void k_scatter(const int* __restrict__ es, const int* __restrict__ ed,
                          int* __restrict__ cur, unsigned int* __restrict__ csr, int ne) {
  int i = (blockIdx.x * 256 + threadIdx.x) * 4;
  if (i + 4 <= ne) {
    int4 s4 = *(const int4*)(es + i);
    int4 d4 = *(const int4*)(ed + i);
    csr[atomicAdd(&cur[d4.x], 1)] = (unsigned int)s4.x;
    csr[atomicAdd(&cur[d4.y], 1)] = (unsigned int)s4.y;
    csr[atomicAdd(&cur[d4.z], 1)] = (unsigned int)s4.z;
    csr[atomicAdd(&cur[d4.w], 1)] = (unsigned int)s4.w;
  } else {
    for (int j = i; j < ne; j++) csr[atomicAdd(&cur[ed[j]], 1)] = (unsigned int)es[j];
  }
}

// ---------------- regroup region segments by dst; emit per-dst rp ----------------

__global__ __launch_bounds__(256) void k_group(unsigned int* __restrict__ csr,
                                               const int* __restrict__ rbase,
                                               int* __restrict__ rp,
                                               int* __restrict__ flags, int nd, int nr) {
  int r = blockIdx.x;
  int d0 = r << RSHIFT;
  int d1 = min(d0 + RDST, nd);
  int start = rbase[r];
  int end = rbase[r + 1];
  int n = end - start;
  int t = threadIdx.x;
  if (r == nr - 1 && t == 0) rp[nd] = end;
  if (n > IMG_CAP) {
    if (t == 0) flags[r] = 1;
    if (t < d1 - d0) rp[d0 + t] = start;
    return;
  }
  __shared__ int cnt[RDST];
  __shared__ int off[RDST];
  __shared__ unsigned int img[IMG_CAP];
  if (t == 0) flags[r] = 0;
  if (t < RDST) cnt[t] = 0;
  __syncthreads();
  for (int i = t; i < n; i += 256) atomicAdd(&cnt[(csr[start + i] >> 26) & (RDST - 1)], 1);
  __syncthreads();
  if (t < RDST) {
    int x = cnt[t];
    int inc = x;
#pragma unroll
    for (int o = 1; o < RDST; o <<= 1) { int y = __shfl_up(inc, o, 64); if (t >= o) inc += y; }
    off[t] = inc - x;
    if (t < d1 - d0) rp[d0 + t] = start + inc - x;
  }
  __syncthreads();
  for (int i = t; i < n; i += 256) {
    unsigned int v = csr[start + i];
    int p = atomicAdd(&off[(v >> 26) & (RDST - 1)], 1);
    img[p] = v;
  }
  __syncthreads();
  for (int i = t; i < n; i += 256) csr[start + i] = img[i];
}

// ---------------- aggregation: bf16 gather, wave per dst, 4 waves/block ----------------

__global__ __launch_bounds__(256) void k_agg_bf(const int* __restrict__ rp, const unsigned int* __restrict__ csr,
                                                const unsigned int* __restrict__ hs,
                                                const float* __restrict__ ginv,
                                                const int* __restrict__ flags,
                                                float* __restrict__ out, int nd) {
  int d = blockIdx.x * 4 + (threadIdx.x >> 6);
  if (d >= nd) return;
  int lane = threadIdx.x & 63;
  float gi = ginv[0];

  if (flags[d >> RSHIFT]) {
    int rs = rp[(d >> RSHIFT) << RSHIFT];
    int re = rp[min((((d >> RSHIFT) + 1) << RSHIFT), nd)];
    unsigned int dl = (unsigned int)(d & (RDST - 1));
    float a0 = 0.f, a1 = 0.f;
    int c = 0;
    for (int e = rs; e < re; ++e) {
      unsigned int v = csr[e];
      if (((v >> 26) & (RDST - 1)) == dl) {
        c++;
        unsigned int u = hs[(size_t)(v & SRCMASK) * 64 + lane];
        a0 += __uint_as_float(u << 16);
        a1 += __uint_as_float(u & 0xffff0000u);
      }
    }
    float sc = gi / fmaxf((float)c, 1.0f);
    *(float2*)(out + (size_t)d * FEAT + lane * 2) = make_float2(a0 * sc, a1 * sc);
    return;
  }

  int beg = rp[d], end = rp[d + 1];
  float sc = gi / fmaxf((float)(end - beg), 1.0f);
  int q = lane >> 4;
  int fw = (lane & 15) * 4;
  float acc[8] = {0, 0, 0, 0, 0, 0, 0, 0};
  int e = beg;
  for (; e + 16 <= end; e += 16) {
    int s0 = csr[e + q] & SRCMASK;
    int s1 = csr[e + 4 + q] & SRCMASK;
    int s2 = csr[e + 8 + q] & SRCMASK;
    int s3 = csr[e + 12 + q] & SRCMASK;
    uint4 a = *(const uint4*)(hs + (size_t)s0 * 64 + fw);
    uint4 b = *(const uint4*)(hs + (size_t)s1 * 64 + fw);
    uint4 c = *(const uint4*)(hs + (size_t)s2 * 64 + fw);
    uint4 dd = *(const uint4*)(hs + (size_t)s3 * 64 + fw);
    acc8(acc, a); acc8(acc, b); acc8(acc, c); acc8(acc, dd);
  }
  for (; e + 4 <= end; e += 4) {
    int s0 = csr[e + q] & SRCMASK;
    uint4 a = *(const uint4*)(hs + (size_t)s0 * 64 + fw);
    acc8(acc, a);
  }
  int rem = end - e;
  if (q < rem) {
    int s0 = csr[e + q] & SRCMASK;
    uint4 a = *(const uint4*)(hs + (size_t)s0 * 64 + fw);
    acc8(acc, a);
  }
#pragma unroll
  for (int j = 0; j < 8; j++) {
    acc[j] += __shfl_xor(acc[j], 16, 64);
    acc[j] += __shfl_xor(acc[j], 32, 64);
  }
  if (lane < 16) {
    float4 o0 = make_float4(acc[0] * sc, acc[1] * sc, acc[2] * sc, acc[3] * sc);
    float4 o1 = make_float4(acc[4] * sc, acc[5] * sc, acc[6] * sc, acc[7] * sc);
    float* p = out + (size_t)d * FEAT + fw * 2;
    *(float4*)p = o0;
    *(float4*)(p + 4) = o1;
  }
}

// fallback f32 aggregation (if workspace too small for hs; mv already normalized)
__global__ __launch_bounds__(256) void k_agg_f32(const int* __restrict__ rp, const unsigned int* __restrict__ csr,
                                                 const float* __restrict__ h, const float* __restrict__ mv,
                                                 const int* __restrict__ flags,
                                                 float* __restrict__ rst, int nd) {
  int d = blockIdx.x * 4 + (threadIdx.x >> 6);
  if (d >= nd) return;
  int lane = threadIdx.x & 63;
  float ax = 0.f, ay = 0.f;
  if (flags[d >> RSHIFT]) {
    int rs = rp[(d >> RSHIFT) << RSHIFT];
    int re = rp[min((((d >> RSHIFT) + 1) << RSHIFT), nd)];
    unsigned int dl = (unsigned int)(d & (RDST - 1));
    int c = 0;
    for (int e = rs; e < re; ++e) {
      unsigned int v = csr[e];
      if (((v >> 26) & (RDST - 1)) == dl) {
        c++;
        int s = v & SRCMASK;
        float m = mv[s];
        float2 vv = *(const float2*)(h + (size_t)s * FEAT + lane * 2);
        ax += vv.x * m; ay += vv.y * m;
      }
    }
    float inv = 1.0f / fmaxf((float)c, 1.0f);
    *(float2*)(rst + (size_t)d * FEAT + lane * 2) = make_float2(ax * inv, ay * inv);
    return;
  }
  int beg = rp[d], end = rp[d + 1];
  float inv = 1.0f / fmaxf((float)(end - beg), 1.0f);
  for (int e = beg; e < end; ++e) {
    int s = csr[e] & SRCMASK;
    float m = mv[s];
    float2 vv = *(const float2*)(h + (size_t)s * FEAT + lane * 2);
    ax += vv.x * m; ay += vv.y * m;
  }
  *(float2*)(rst + (size_t)d * FEAT + lane * 2) = make_float2(ax * inv, ay * inv);
}

// ---------------- in-place dense transform: out = rst @ W + b ----------------

__global__ __launch_bounds__(256) void k_gemm(float* __restrict__ out, const float* __restrict__ W,
                                              const float* __restrict__ b, int nd) {
  __shared__ float Ws[FEAT * FEAT];
  __shared__ float Rs[32][FEAT];
  int t = threadIdx.x;
  for (int i = t * 4; i < FEAT * FEAT; i += 1024) *(float4*)(Ws + i) = *(const float4*)(W + i);
  int c0 = (t & 31) * 4;
  int rg = (t >> 5) * 4;
  float4 bb = *(const float4*)(b + c0);
  for (int ch = 0; ch < 4; ch++) {
    int r0 = blockIdx.x * 128 + ch * 32;
    if (r0 >= nd) break;
    int rows = min(32, nd - r0);
    __syncthreads();
    for (int i = t; i < rows * FEAT; i += 256) Rs[i >> 7][i & 127] = out[(size_t)r0 * FEAT + i];
    __syncthreads();
    float acc[4][4];
#pragma unroll
    for (int i = 0; i < 4; i++) { acc[i][0] = bb.x; acc[i][1] = bb.y; acc[i][2] = bb.z; acc[i][3] = bb.w; }
    for (int k = 0; k < FEAT; k += 4) {
#pragma unroll
      for (int kk = 0; kk < 4; kk++) {
        float4 wv = *(const float4*)(&Ws[(k + kk) * FEAT + c0]);
#pragma unroll
        for (int i = 0; i < 4; i++) {
          float rv = Rs[rg + i][k + kk];
          acc[i][0] += rv * wv.x;
          acc[i][1] += rv * wv.y;
          acc[i][2] += rv * wv.z;
          acc[i][3] += rv * wv.w;
        }
      }
    }
#pragma unroll
    for (int i = 0; i < 4; i++) {
      int r = rg + i;
      if (r < rows) *(float4*)(out + (size_t)(r0 + r) * FEAT + c0) = *(float4*)acc[i];
    }
  }
}

// ---------------- launcher ----------------

extern "C" void kernel_launch(void* const* d_in, const int* in_sizes, int n_in,
                              void* d_out, int out_size, void* d_ws, size_t ws_size,
                              hipStream_t stream) {
  const float* h    = (const float*)d_in[0];
  const int*   ids  = (const int*)d_in[1];
  const int*   es   = (const int*)d_in[2];
  const int*   ed   = (const int*)d_in[3];
  const float* mask = (const float*)d_in[4];
  const float* W    = (const float*)d_in[5];
  const float* b    = (const float*)d_in[6];
  float* out = (float*)d_out;

  const int NS = in_sizes[1];
  const int E  = in_sizes[2];
  const int H  = in_sizes[6];
  const int ND = (out_size - NS) / H;
  const int NR = (ND + RDST - 1) >> RSHIFT;
  const bool use_part = (NR <= MAXR);

  float* mv = out + (size_t)ND * H;

  char* w = (char*)d_ws;
  size_t used = 0;
  auto carve = [&](size_t bytes) -> char* {
    char* p = w + used;
    used += (bytes + 255) & ~(size_t)255;
    return p;
  };
  float* pbuf = (float*)carve(4096 * sizeof(float));
  float* ginv = (float*)carve(256);
  int* flags = (int*)carve((size_t)NR * sizeof(int));
  int* rp    = (int*)carve((size_t)(ND + 1) * sizeof(int));
  int* rtot  = (int*)carve((size_t)NR * sizeof(int));
  int* rbase = (int*)carve((size_t)(NR + 1) * sizeof(int));
  int* deg   = (int*)carve((size_t)ND * sizeof(int));   // fallback only
  int* cur   = (int*)carve((size_t)ND * sizeof(int));   // fallback only
  int* ghist = (int*)carve((size_t)NR * NB * sizeof(int));
  unsigned int* csr = (unsigned int*)carve((size_t)E * sizeof(int));
  size_t hs_bytes = (size_t)NS * FEAT * 2;
  unsigned int* hs = nullptr;
  if (used + hs_bytes + 256 <= ws_size) hs = (unsigned int*)carve(hs_bytes);

  const int gb = (NS + 255) / 256;
  const int db = ((E + 3) / 4 + 255) / 256;
  const int chunk = ((E + NB - 1) / NB + 3) & ~3;
  const int hb = use_part ? NB : 0;
  const int n2 = hs ? NS * (FEAT / 4) : 0;
  const int cb = hs ? (n2 + 255) / 256 : 0;

  kA<<<gb + hb + cb, 256, 0, stream>>>(mask, ids, mv, pbuf, NS, ed, E, gb, hb,
                                       ghist, chunk, NR, h, (uint2*)hs);

  if (use_part) {
    kB1<<<NR + 1, 256, 0, stream>>>(ghist, rtot, NR, pbuf, ginv, gb);
    k_part<<<NB, 256, 0, stream>>>(es, ed, ghist, rtot, rbase, csr, E, chunk, NR, mv, NS, ginv);
    k_group<<<NR, 256, 0, stream>>>(csr, rbase, rp, flags, ND, NR);
  } else {
    kB1<<<1, 256, 0, stream>>>(ghist, rtot, 0, pbuf, ginv, gb);
    hipMemsetAsync(deg, 0, (size_t)ND * sizeof(int), stream);
    hipMemsetAsync(flags, 0, (size_t)NR * sizeof(int), stream);
    k_deg<<<db, 256, 0, stream>>>(ed, deg, E);
    k_scan<<<1, 1024, 0, stream>>>(deg, rp, cur, ND, rp + ND);
    k_norm<<<(NS + 255) / 256, 256, 0, stream>>>(mv, ginv, NS);
    k_scatter<<<db, 256, 0, stream>>>(es, ed, cur, csr, E);
  }

  if (hs) k_agg_bf<<<(ND + 3) / 4, 256, 0, stream>>>(rp, csr, hs, ginv, flags, out, ND);
  else    k_agg_f32<<<(ND + 3) / 4, 256, 0, stream>>>(rp, csr, h, mv, flags, out, ND);
  k_gemm<<<(ND + 127) / 128, 256, 0, stream>>>(out, W, b, ND);
}